// Round 1
// baseline (222.261 us; speedup 1.0000x reference)
//
#include <hip/hip_runtime.h>

#define BATCH 64
#define T 480000
#define T4 (T / 4)          // 120000 float4 per row
#define NTAPS 16

__global__ __launch_bounds__(256) void fir_apply_kernel(
    const float* __restrict__ x,
    const float* __restrict__ b,
    float* __restrict__ y)
{
    const int gid = blockIdx.x * blockDim.x + threadIdx.x;
    if (gid >= BATCH * T4) return;

    const int row  = gid / T4;
    const int col4 = gid - row * T4;

    const float4* xr = (const float4*)(x + (size_t)row * T);

    // s[0..19] = x[row, 4*col4-16 .. 4*col4+3], zeros for t < 0.
    // Chunks are float4-aligned, so each is entirely t>=0 or entirely t<0.
    float s[20];
#pragma unroll
    for (int m = 0; m < 5; ++m) {
        const int c = col4 - 4 + m;
        float4 v;
        if (c >= 0) {
            v = xr[c];
        } else {
            v = make_float4(0.f, 0.f, 0.f, 0.f);
        }
        s[4 * m + 0] = v.x;
        s[4 * m + 1] = v.y;
        s[4 * m + 2] = v.z;
        s[4 * m + 3] = v.w;
    }

    // Taps: thread-uniform, literal-indexed -> scalar loads, L2-resident.
    float tap[NTAPS];
#pragma unroll
    for (int k = 0; k < NTAPS; ++k) tap[k] = b[k];

    // y[t] = sum_k tap[k] * x[t-k];  t = 4*col4 + j  ->  s index 16 + j - k
    float acc[4];
#pragma unroll
    for (int j = 0; j < 4; ++j) {
        float a = 0.f;
#pragma unroll
        for (int k = 0; k < NTAPS; ++k) {
            a += tap[k] * s[16 + j - k];
        }
        acc[j] = a;
    }

    float4* yr = (float4*)(y + (size_t)row * T);
    yr[col4] = make_float4(acc[0], acc[1], acc[2], acc[3]);
}

extern "C" void kernel_launch(void* const* d_in, const int* in_sizes, int n_in,
                              void* d_out, int out_size, void* d_ws, size_t ws_size,
                              hipStream_t stream)
{
    const float* x = (const float*)d_in[0];
    const float* b = (const float*)d_in[1];
    float* y = (float*)d_out;

    const int total4 = BATCH * T4;              // 7,680,000 float4 outputs
    const int block = 256;
    const int grid = (total4 + block - 1) / block;  // exactly 30000

    fir_apply_kernel<<<grid, block, 0, stream>>>(x, b, y);
}